// Round 3
// baseline (590.232 us; speedup 1.0000x reference)
//
#include <hip/hip_runtime.h>
#include <cstdint>
#include <cstddef>

#define HW 14400
#define WIDTH 120
#define S_TOT 110

typedef unsigned short u16;
typedef __attribute__((ext_vector_type(8))) short bf16x8;
typedef __attribute__((ext_vector_type(4))) float f32x4;

__device__ __forceinline__ u16 f2bf(float x) {
  unsigned u = __float_as_uint(x);
  unsigned r = (u + 0x7fffu + ((u >> 16) & 1u)) >> 16;
  return (u16)r;
}
__device__ __forceinline__ float bf2f(u16 h) {
  return __uint_as_float((unsigned)h << 16);
}

__device__ __forceinline__ void async16(void* lds, const void* g) {
  __builtin_amdgcn_global_load_lds(
      (const __attribute__((address_space(1))) void*)g,
      (__attribute__((address_space(3))) void*)lds, 16, 0, 0);
}

// ---------------------------------------------------------------------------
// Pyramid pooling: in [nplanes][14400] -> out [nplanes][110]
// ---------------------------------------------------------------------------
__global__ __launch_bounds__(256) void pool_kernel(const float* __restrict__ in,
                                                   float* __restrict__ outp) {
  __shared__ float part[576];
  const float* plane = in + (size_t)blockIdx.x * HW;
  int t = threadIdx.x;
  for (int bb = t; bb < 576; bb += 256) {
    int by = bb / 24, bx = bb % 24;
    const float* p0 = plane + (by * 5) * WIDTH + bx * 5;
    float s = 0.f;
#pragma unroll
    for (int yy = 0; yy < 5; ++yy)
#pragma unroll
      for (int xx = 0; xx < 5; ++xx) s += p0[yy * WIDTH + xx];
    part[bb] = s;
  }
  __syncthreads();
  if (t < S_TOT) {
    float s = 0.f;
    if (t == 0) {
      for (int i = 0; i < 576; ++i) s += part[i];
      s *= (1.f / 14400.f);
    } else if (t < 10) {
      int idx = t - 1, i = idx / 3, j = idx % 3;
      for (int a = 0; a < 8; ++a)
        for (int c = 0; c < 8; ++c) s += part[(i * 8 + a) * 24 + (j * 8 + c)];
      s *= (1.f / 1600.f);
    } else if (t < 46) {
      int idx = t - 10, i = idx / 6, j = idx % 6;
      for (int a = 0; a < 4; ++a)
        for (int c = 0; c < 4; ++c) s += part[(i * 4 + a) * 24 + (j * 4 + c)];
      s *= (1.f / 400.f);
    } else {
      int idx = t - 46, i = idx / 8, j = idx % 8;
      for (int a = 0; a < 3; ++a)
        for (int c = 0; c < 3; ++c) s += part[(i * 3 + a) * 24 + (j * 3 + c)];
      s *= (1.f / 225.f);
    }
    outp[(size_t)blockIdx.x * S_TOT + t] = s;
  }
}

// ---------------------------------------------------------------------------
// Split fp32 weight -> bf16 hi/lo (elementwise)
// ---------------------------------------------------------------------------
__global__ __launch_bounds__(256) void convert_w(const float* __restrict__ in,
                                                 u16* __restrict__ hi,
                                                 u16* __restrict__ lo, int n) {
  int i = blockIdx.x * 256 + threadIdx.x;
  if (i < n) {
    float v = in[i];
    u16 h = f2bf(v);
    hi[i] = h;
    lo[i] = f2bf(v - bf2f(h));
  }
}

// ---------------------------------------------------------------------------
// X [b][CIN][14400] fp32 -> XT hi/lo [b][14400][CIN] bf16 (transpose + split)
// ---------------------------------------------------------------------------
template <int CIN>
__global__ __launch_bounds__(256) void convert_t(const float* __restrict__ X,
                                                 u16* __restrict__ xth,
                                                 u16* __restrict__ xtl) {
  __shared__ float ls[64][65];
  int b = blockIdx.z;
  int n0 = blockIdx.x * 64, k0 = blockIdx.y * 64;
  int t = threadIdx.x;
  int rt = t >> 4, c4 = (t & 15) * 4;
#pragma unroll
  for (int rr = 0; rr < 4; ++rr) {
    int kk = rr * 16 + rt;
    float4 v = *(const float4*)&X[((size_t)(b * CIN + k0 + kk)) * HW + n0 + c4];
    ls[kk][c4] = v.x; ls[kk][c4 + 1] = v.y; ls[kk][c4 + 2] = v.z; ls[kk][c4 + 3] = v.w;
  }
  __syncthreads();
#pragma unroll
  for (int rr = 0; rr < 4; ++rr) {
    int nn = rr * 16 + rt;
    float v0 = ls[c4 + 0][nn], v1 = ls[c4 + 1][nn], v2 = ls[c4 + 2][nn], v3 = ls[c4 + 3][nn];
    ushort4 oh, ol;
    oh.x = f2bf(v0); ol.x = f2bf(v0 - bf2f(oh.x));
    oh.y = f2bf(v1); ol.y = f2bf(v1 - bf2f(oh.y));
    oh.z = f2bf(v2); ol.z = f2bf(v2 - bf2f(oh.z));
    oh.w = f2bf(v3); ol.w = f2bf(v3 - bf2f(oh.w));
    size_t idx = ((size_t)(b * HW + n0 + nn)) * CIN + k0 + c4;
    *(ushort4*)&xth[idx] = oh;
    *(ushort4*)&xtl[idx] = ol;
  }
}

// ---------------------------------------------------------------------------
// Split-bf16 MFMA GEMM v4:  C[b][m][n] = epi( sum_k A[m][k]*B[b][n][k] )
//  Tile: BM=128, BN=192, BK=32. 8 waves (512 thr), wave grid 2m x 4n:
//  wave (wm,wn) computes 4 m-frags x 3 n-frags (acc[4][3] = 48 VGPR).
//  Staged bytes/MFMA: 142 B (vs 208 at BN=64) -- A-restage traffic /3.
//  Frag-major dbuf LDS (A 16 frags + B 24 frags) = 40 KB/step, 80 KB total
//  -> 2 blocks/CU, 16 waves/CU = 4 waves/SIMD (launch_bounds forces
//  VGPR<=128). global_load_lds staging, 5 loads/wave/step, 2-phase
//  pipeline (stage(ks+1) issued before compute(ks), one barrier/step).
// ---------------------------------------------------------------------------
template <int K, int M_TOT, bool BNRELU>
__global__ __launch_bounds__(512, 4) void gemm_mfma(
    const u16* __restrict__ Ah, const u16* __restrict__ Al,
    const u16* __restrict__ Bh, const u16* __restrict__ Bl,
    float* __restrict__ C,
    const float* __restrict__ p0, const float* __restrict__ p1,
    const float* __restrict__ p2, const float* __restrict__ p3,
    const float* __restrict__ p4) {
  constexpr int NSTEP = K / 32;
  // frag-major: [buf][frag][lane*8]; A: frags 0..7 hi, 8..15 lo (m-frags)
  // B: frags 0..11 hi, 12..23 lo (n-frags)
  __shared__ alignas(16) u16 sA[2][16][512];
  __shared__ alignas(16) u16 sB[2][24][512];

  int t = threadIdx.x, w = t >> 6, l = t & 63;
  int wm = w >> 2, wn = w & 3;
  int b = blockIdx.z;
  int n0 = blockIdx.x * 192;
  int m0 = blockIdx.y * 128;

  int fr = l & 15, fkc = l >> 4;  // fragment row, k-chunk (of 8 u16)
  const size_t bOff = (size_t)b * HW;

  // stage one 32-k slice: 16 A frags + 24 B frags = 40 x 1KB; 5 per wave
  auto stage = [&](int ks, int buf) {
    int k0 = ks * 32;
#pragma unroll
    for (int c = 0; c < 5; ++c) {
      int i = w * 5 + c;
      const u16* g;
      u16* d;
      if (i < 8) {
        g = Ah + (size_t)(m0 + i * 16 + fr) * K + k0 + fkc * 8;
        d = &sA[buf][i][0];
      } else if (i < 16) {
        g = Al + (size_t)(m0 + (i - 8) * 16 + fr) * K + k0 + fkc * 8;
        d = &sA[buf][i][0];
      } else if (i < 28) {
        g = Bh + (bOff + n0 + (i - 16) * 16 + fr) * (size_t)K + k0 + fkc * 8;
        d = &sB[buf][i - 16][0];
      } else {
        g = Bl + (bOff + n0 + (i - 28) * 16 + fr) * (size_t)K + k0 + fkc * 8;
        d = &sB[buf][i - 16][0];  // i-16 in 12..23 -> lo frags
      }
      async16(d, g);
    }
  };

  f32x4 acc[4][3];
#pragma unroll
  for (int i = 0; i < 4; ++i)
#pragma unroll
    for (int j = 0; j < 3; ++j) acc[i][j] = (f32x4){0.f, 0.f, 0.f, 0.f};

  stage(0, 0);

  for (int ks = 0; ks < NSTEP; ++ks) {
    __syncthreads();  // drains stage(ks); buf^1 reads of iter ks-1 all done
    if (ks + 1 < NSTEP) stage(ks + 1, (ks + 1) & 1);  // overlap with compute
    int cur = ks & 1;
    bf16x8 bh[3], bl[3];
#pragma unroll
    for (int nt = 0; nt < 3; ++nt) {
      bh[nt] = *(const bf16x8*)&sB[cur][wn * 3 + nt][l * 8];
      bl[nt] = *(const bf16x8*)&sB[cur][12 + wn * 3 + nt][l * 8];
    }
#pragma unroll
    for (int mt = 0; mt < 4; ++mt) {
      bf16x8 ah = *(const bf16x8*)&sA[cur][wm * 4 + mt][l * 8];
      bf16x8 al = *(const bf16x8*)&sA[cur][8 + wm * 4 + mt][l * 8];
#pragma unroll
      for (int nt = 0; nt < 3; ++nt) {
        acc[mt][nt] = __builtin_amdgcn_mfma_f32_16x16x32_bf16(ah, bh[nt], acc[mt][nt], 0, 0, 0);
        acc[mt][nt] = __builtin_amdgcn_mfma_f32_16x16x32_bf16(ah, bl[nt], acc[mt][nt], 0, 0, 0);
        acc[mt][nt] = __builtin_amdgcn_mfma_f32_16x16x32_bf16(al, bh[nt], acc[mt][nt], 0, 0, 0);
      }
    }
  }

  // epilogue: params via broadcast float4 loads (same addr across fr lanes)
#pragma unroll
  for (int mt = 0; mt < 4; ++mt) {
    int mb = m0 + (wm * 4 + mt) * 16 + (l >> 4) * 4;  // 4 consecutive m rows
    float iv[4], ad[4];
    if (BNRELU) {
      float4 g0 = *(const float4*)&p0[mb];
      float4 g1 = *(const float4*)&p1[mb];
      float4 g2 = *(const float4*)&p2[mb];
      float4 g3 = *(const float4*)&p3[mb];
      float4 g4 = *(const float4*)&p4[mb];
      iv[0] = g1.x * rsqrtf(g4.x + 1e-5f);
      iv[1] = g1.y * rsqrtf(g4.y + 1e-5f);
      iv[2] = g1.z * rsqrtf(g4.z + 1e-5f);
      iv[3] = g1.w * rsqrtf(g4.w + 1e-5f);
      ad[0] = (g0.x - g3.x) * iv[0] + g2.x;
      ad[1] = (g0.y - g3.y) * iv[1] + g2.y;
      ad[2] = (g0.z - g3.z) * iv[2] + g2.z;
      ad[3] = (g0.w - g3.w) * iv[3] + g2.w;
    } else {
      float4 g0 = *(const float4*)&p0[mb];
      ad[0] = g0.x; ad[1] = g0.y; ad[2] = g0.z; ad[3] = g0.w;
    }
#pragma unroll
    for (int nt = 0; nt < 3; ++nt) {
      int n = n0 + (wn * 3 + nt) * 16 + fr;
#pragma unroll
      for (int r = 0; r < 4; ++r) {
        float v = acc[mt][nt][r];
        if (BNRELU)
          v = fmaxf(v * iv[r] + ad[r], 0.f);
        else
          v = v + ad[r];
        C[((size_t)(b * M_TOT) + mb + r) * HW + n] = v;
      }
    }
  }
}

// ---------------------------------------------------------------------------
// valueT[b][cv][128] hi/lo = Wv[cv,:] . xp[b,:,s] + bv[cv]  (s>=110 -> 0)
// ---------------------------------------------------------------------------
__global__ __launch_bounds__(256) void value_kernel(
    const float* __restrict__ Wv, const float* __restrict__ xp,
    const float* __restrict__ bv, u16* __restrict__ vth,
    u16* __restrict__ vtl) {
  int b = blockIdx.x >> 7, s = blockIdx.x & 127;
  int t = threadIdx.x;
  size_t o = ((size_t)(b * 256 + t)) * 128 + s;
  if (s >= S_TOT) { vth[o] = 0; vtl[o] = 0; return; }
  __shared__ float xs[512];
  for (int i = t; i < 512; i += 256) xs[i] = xp[((size_t)b * 512 + i) * S_TOT + s];
  __syncthreads();
  float accv = 0.f;
  const float* wv = Wv + (size_t)t * 512;
  for (int k = 0; k < 512; k += 4) {
    float4 w4 = *(const float4*)&wv[k];
    accv += w4.x * xs[k] + w4.y * xs[k + 1] + w4.z * xs[k + 2] + w4.w * xs[k + 3];
  }
  accv += bv[t];
  u16 h = f2bf(accv);
  vth[o] = h;
  vtl[o] = f2bf(accv - bf2f(h));
}

// ---------------------------------------------------------------------------
// keypT[b][128][256] hi/lo from keyp [b][256][110] fp32 (s>=110 -> 0)
// ---------------------------------------------------------------------------
__global__ __launch_bounds__(256) void convert_key(const float* __restrict__ keyp,
                                                   u16* __restrict__ kth,
                                                   u16* __restrict__ ktl) {
  int b = blockIdx.x;
  int t = threadIdx.x;
  for (int i = t; i < 128 * 256; i += 256) {
    int s = i >> 8, c = i & 255;
    float v = (s < S_TOT) ? keyp[((size_t)(b * 256 + c)) * S_TOT + s] : 0.f;
    u16 h = f2bf(v);
    size_t o = ((size_t)(b * 128 + s)) * 256 + c;
    kth[o] = h;
    ktl[o] = f2bf(v - bf2f(h));
  }
}

// ---------------------------------------------------------------------------
// MFMA attention v2. Per block: 64 pixels, 4 waves. (unchanged)
// ---------------------------------------------------------------------------
__global__ __launch_bounds__(256) void attn_mfma(
    const u16* __restrict__ qh, const u16* __restrict__ ql,
    const u16* __restrict__ kh, const u16* __restrict__ kl,
    const u16* __restrict__ vh, const u16* __restrict__ vl,
    u16* __restrict__ aggh, u16* __restrict__ aggl) {
  __shared__ alignas(16) u16 lds[17408];
  int b = blockIdx.y, pix0 = blockIdx.x * 64;
  int t = threadIdx.x, w = t >> 6, l = t & 63;
  int fr = l & 15, q = l >> 4;

  const u16* kbase_h = kh + (size_t)b * 128 * 256;
  const u16* kbase_l = kl + (size_t)b * 128 * 256;

  f32x4 acc[8];
#pragma unroll
  for (int st = 0; st < 8; ++st) acc[st] = (f32x4){0.f, 0.f, 0.f, 0.f};

  const u16* qbh = qh + ((size_t)(b * HW + pix0 + w * 16 + fr)) * 256 + q * 8;
  const u16* qbl = ql + ((size_t)(b * HW + pix0 + w * 16 + fr)) * 256 + q * 8;

  auto stageK = [&](int ks, int buf) {
    int c0 = ks * 32;
#pragma unroll
    for (int j = 0; j < 4; ++j) {
      int i = t + j * 256;
      int half = i >> 9;
      int idx = i & 511;
      int st = idx >> 6, ll = idx & 63;
      const u16* src = (half ? kbase_l : kbase_h) +
                       (st * 16 + (ll & 15)) * 256 + c0 + (ll >> 4) * 8;
      async16(&lds[buf * 8192 + half * 4096 + idx * 8], src);
    }
  };

  stageK(0, 0);
  for (int ks = 0; ks < 8; ++ks) {
    __syncthreads();
    if (ks < 7) stageK(ks + 1, (ks + 1) & 1);
    bf16x8 ah = *(const bf16x8*)(qbh + ks * 32);
    bf16x8 al = *(const bf16x8*)(qbl + ks * 32);
    const u16* kb = &lds[(ks & 1) * 8192 + l * 8];
#pragma unroll
    for (int st = 0; st < 8; ++st) {
      bf16x8 bh = *(const bf16x8*)(kb + st * 512);
      bf16x8 bl = *(const bf16x8*)(kb + 4096 + st * 512);
      acc[st] = __builtin_amdgcn_mfma_f32_16x16x32_bf16(ah, bh, acc[st], 0, 0, 0);
      acc[st] = __builtin_amdgcn_mfma_f32_16x16x32_bf16(ah, bl, acc[st], 0, 0, 0);
      acc[st] = __builtin_amdgcn_mfma_f32_16x16x32_bf16(al, bh, acc[st], 0, 0, 0);
    }
  }

#pragma unroll
  for (int st = 0; st < 8; ++st)
#pragma unroll
    for (int r = 0; r < 4; ++r) acc[st][r] *= 0.0625f;
  if (fr >= 14) {
#pragma unroll
    for (int r = 0; r < 4; ++r) acc[6][r] = -1e30f;
  }
#pragma unroll
  for (int r = 0; r < 4; ++r) acc[7][r] = -1e30f;

#pragma unroll
  for (int r = 0; r < 4; ++r) {
    float m = -1e30f;
#pragma unroll
    for (int st = 0; st < 8; ++st) m = fmaxf(m, acc[st][r]);
    m = fmaxf(m, __shfl_xor(m, 1));
    m = fmaxf(m, __shfl_xor(m, 2));
    m = fmaxf(m, __shfl_xor(m, 4));
    m = fmaxf(m, __shfl_xor(m, 8));
    float s = 0.f;
#pragma unroll
    for (int st = 0; st < 8; ++st) {
      float e = __expf(acc[st][r] - m);
      acc[st][r] = e;
      s += e;
    }
    s += __shfl_xor(s, 1);
    s += __shfl_xor(s, 2);
    s += __shfl_xor(s, 4);
    s += __shfl_xor(s, 8);
    float inv = 1.f / s;
#pragma unroll
    for (int st = 0; st < 8; ++st) acc[st][r] *= inv;
  }

  __syncthreads();

  int prow = w * 16 + q * 4;
#pragma unroll
  for (int st = 0; st < 8; ++st) {
    int s = st * 16 + fr;
#pragma unroll
    for (int r = 0; r < 4; ++r) {
      float v = acc[st][r];
      u16 h = f2bf(v);
      lds[(prow + r) * 136 + s] = h;
      lds[8704 + (prow + r) * 136 + s] = f2bf(v - bf2f(h));
    }
  }
  __syncthreads();

  f32x4 oacc[4][4];
#pragma unroll
  for (int nt = 0; nt < 4; ++nt)
#pragma unroll
    for (int pt = 0; pt < 4; ++pt) oacc[nt][pt] = (f32x4){0.f, 0.f, 0.f, 0.f};

  const u16* vbh = vh + ((size_t)(b * 256 + w * 64 + fr)) * 128 + q * 8;
  const u16* vbl = vl + ((size_t)(b * 256 + w * 64 + fr)) * 128 + q * 8;

#pragma unroll
  for (int kc = 0; kc < 4; ++kc) {
    bf16x8 ph[4], pl[4];
#pragma unroll
    for (int pt = 0; pt < 4; ++pt) {
      ph[pt] = *(const bf16x8*)&lds[(pt * 16 + fr) * 136 + kc * 32 + q * 8];
      pl[pt] = *(const bf16x8*)&lds[8704 + (pt * 16 + fr) * 136 + kc * 32 + q * 8];
    }
#pragma unroll
    for (int nt = 0; nt < 4; ++nt) {
      bf16x8 a_h = *(const bf16x8*)(vbh + (size_t)nt * 16 * 128 + kc * 32);
      bf16x8 a_l = *(const bf16x8*)(vbl + (size_t)nt * 16 * 128 + kc * 32);
#pragma unroll
      for (int pt = 0; pt < 4; ++pt) {
        oacc[nt][pt] = __builtin_amdgcn_mfma_f32_16x16x32_bf16(a_h, ph[pt], oacc[nt][pt], 0, 0, 0);
        oacc[nt][pt] = __builtin_amdgcn_mfma_f32_16x16x32_bf16(a_h, pl[pt], oacc[nt][pt], 0, 0, 0);
        oacc[nt][pt] = __builtin_amdgcn_mfma_f32_16x16x32_bf16(a_l, ph[pt], oacc[nt][pt], 0, 0, 0);
      }
    }
  }

#pragma unroll
  for (int nt = 0; nt < 4; ++nt) {
#pragma unroll
    for (int pt = 0; pt < 4; ++pt) {
      ushort4 oh, ol;
      float v0 = oacc[nt][pt][0], v1 = oacc[nt][pt][1];
      float v2 = oacc[nt][pt][2], v3 = oacc[nt][pt][3];
      oh.x = f2bf(v0); ol.x = f2bf(v0 - bf2f(oh.x));
      oh.y = f2bf(v1); ol.y = f2bf(v1 - bf2f(oh.y));
      oh.z = f2bf(v2); ol.z = f2bf(v2 - bf2f(oh.z));
      oh.w = f2bf(v3); ol.w = f2bf(v3 - bf2f(oh.w));
      size_t o = ((size_t)(b * HW + pix0 + pt * 16 + fr)) * 256 + (w * 4 + nt) * 16 + q * 4;
      *(ushort4*)&aggh[o] = oh;
      *(ushort4*)&aggl[o] = ol;
    }
  }
}

extern "C" void kernel_launch(void* const* d_in, const int* in_sizes, int n_in,
                              void* d_out, int out_size, void* d_ws, size_t ws_size,
                              hipStream_t stream) {
  (void)in_sizes; (void)n_in; (void)out_size; (void)ws_size;
  const float* x     = (const float*)d_in[0];
  const float* Wk    = (const float*)d_in[1];
  const float* bk    = (const float*)d_in[2];
  const float* gamma = (const float*)d_in[3];
  const float* beta  = (const float*)d_in[4];
  const float* mean  = (const float*)d_in[5];
  const float* var   = (const float*)d_in[6];
  const float* Wv    = (const float*)d_in[7];
  const float* bv    = (const float*)d_in[8];
  const float* Wo    = (const float*)d_in[9];
  const float* bo    = (const float*)d_in[10];
  float* out = (float*)d_out;

  char* p = (char*)d_ws;
  float* kq = (float*)p;      p += (size_t)14745600 * 4;   // 4*256*14400 fp32
  u16* xth = (u16*)p;         p += (size_t)29491200 * 2;   // 4*14400*512 bf16
  u16* xtl = (u16*)p;         p += (size_t)29491200 * 2;
  u16* wkh = (u16*)p;         p += 131072 * 2;
  u16* wkl = (u16*)p;         p += 131072 * 2;
  u16* woh = (u16*)p;         p += 131072 * 2;
  u16* wol = (u16*)p;         p += 131072 * 2;
  float* xp = (float*)p;      p += (size_t)4 * 512 * 110 * 4;
  float* keyp = (float*)p;    p += (size_t)4 * 256 * 110 * 4;
  u16* vth = (u16*)p;         p += (size_t)4 * 256 * 128 * 2;
  u16* vtl = (u16*)p;         p += (size_t)4 * 256 * 128 * 2;
  u16* kth = (u16*)p;         p += (size_t)4 * 128 * 256 * 2;
  u16* ktl = (u16*)p;         p += (size_t)4 * 128 * 256 * 2;
  // aliases: xth/xtl (59MB each) are dead after gemm_kq.
  // first half -> agg hi/lo, second half -> kqT hi/lo
  u16* aggh = xth;
  u16* kqth = xth + (size_t)14745600;
  u16* aggl = xtl;
  u16* kqtl = xtl + (size_t)14745600;

  // weight splits
  convert_w<<<512, 256, 0, stream>>>(Wk, wkh, wkl, 256 * 512);
  convert_w<<<512, 256, 0, stream>>>(Wo, woh, wol, 512 * 256);
  // X -> transposed bf16 hi/lo
  convert_t<512><<<dim3(225, 8, 4), 256, 0, stream>>>(x, xth, xtl);
  // pyramid-pool x (pooling commutes with 1x1 conv for value)
  pool_kernel<<<dim3(4 * 512), dim3(256), 0, stream>>>(x, xp);
  // valueT = split(conv_v(pooled x) + bv), s-padded
  value_kernel<<<dim3(4 * 128), dim3(256), 0, stream>>>(Wv, xp, bv, vth, vtl);
  // kq = relu(BN(conv_k(x)))  [split-bf16 MFMA, BM128xBN192, 8 waves]
  gemm_mfma<512, 256, true><<<dim3(75, 2, 4), 512, 0, stream>>>(
      wkh, wkl, xth, xtl, kq, bk, gamma, beta, mean, var);
  // kqT (query in A-fragment layout)
  convert_t<256><<<dim3(225, 4, 4), 256, 0, stream>>>(kq, kqth, kqtl);
  // key = ppm(kq) -> keypT split, s-padded
  pool_kernel<<<dim3(4 * 256), dim3(256), 0, stream>>>(kq, keyp);
  convert_key<<<dim3(4), dim3(256), 0, stream>>>(keyp, kth, ktl);
  // fused MFMA attention -> agg split bf16
  attn_mfma<<<dim3(225, 4), 256, 0, stream>>>(kqth, kqtl, kth, ktl, vth, vtl,
                                              aggh, aggl);
  // out = conv_out(agg) + bo  [split-bf16 MFMA, BM128xBN192, 8 waves]
  gemm_mfma<256, 512, false><<<dim3(75, 4, 4), 512, 0, stream>>>(
      woh, wol, aggh, aggl, out, bo, nullptr, nullptr, nullptr, nullptr);
}

// Round 4
// 560.000 us; speedup vs baseline: 1.0540x; 1.0540x over previous
//
#include <hip/hip_runtime.h>
#include <cstdint>
#include <cstddef>

#define HW 14400
#define WIDTH 120
#define S_TOT 110

typedef unsigned short u16;
typedef __attribute__((ext_vector_type(8))) short bf16x8;
typedef __attribute__((ext_vector_type(4))) float f32x4;

__device__ __forceinline__ u16 f2bf(float x) {
  unsigned u = __float_as_uint(x);
  unsigned r = (u + 0x7fffu + ((u >> 16) & 1u)) >> 16;
  return (u16)r;
}
__device__ __forceinline__ float bf2f(u16 h) {
  return __uint_as_float((unsigned)h << 16);
}

__device__ __forceinline__ void async16(void* lds, const void* g) {
  __builtin_amdgcn_global_load_lds(
      (const __attribute__((address_space(1))) void*)g,
      (__attribute__((address_space(3))) void*)lds, 16, 0, 0);
}

// ---------------------------------------------------------------------------
// Pyramid pooling: in [nplanes][14400] -> out [nplanes][110]
// ---------------------------------------------------------------------------
__global__ __launch_bounds__(256) void pool_kernel(const float* __restrict__ in,
                                                   float* __restrict__ outp) {
  __shared__ float part[576];
  const float* plane = in + (size_t)blockIdx.x * HW;
  int t = threadIdx.x;
  for (int bb = t; bb < 576; bb += 256) {
    int by = bb / 24, bx = bb % 24;
    const float* p0 = plane + (by * 5) * WIDTH + bx * 5;
    float s = 0.f;
#pragma unroll
    for (int yy = 0; yy < 5; ++yy)
#pragma unroll
      for (int xx = 0; xx < 5; ++xx) s += p0[yy * WIDTH + xx];
    part[bb] = s;
  }
  __syncthreads();
  if (t < S_TOT) {
    float s = 0.f;
    if (t == 0) {
      for (int i = 0; i < 576; ++i) s += part[i];
      s *= (1.f / 14400.f);
    } else if (t < 10) {
      int idx = t - 1, i = idx / 3, j = idx % 3;
      for (int a = 0; a < 8; ++a)
        for (int c = 0; c < 8; ++c) s += part[(i * 8 + a) * 24 + (j * 8 + c)];
      s *= (1.f / 1600.f);
    } else if (t < 46) {
      int idx = t - 10, i = idx / 6, j = idx % 6;
      for (int a = 0; a < 4; ++a)
        for (int c = 0; c < 4; ++c) s += part[(i * 4 + a) * 24 + (j * 4 + c)];
      s *= (1.f / 400.f);
    } else {
      int idx = t - 46, i = idx / 8, j = idx % 8;
      for (int a = 0; a < 3; ++a)
        for (int c = 0; c < 3; ++c) s += part[(i * 3 + a) * 24 + (j * 3 + c)];
      s *= (1.f / 225.f);
    }
    outp[(size_t)blockIdx.x * S_TOT + t] = s;
  }
}

// ---------------------------------------------------------------------------
// Split fp32 weight -> bf16 hi/lo (elementwise)
// ---------------------------------------------------------------------------
__global__ __launch_bounds__(256) void convert_w(const float* __restrict__ in,
                                                 u16* __restrict__ hi,
                                                 u16* __restrict__ lo, int n) {
  int i = blockIdx.x * 256 + threadIdx.x;
  if (i < n) {
    float v = in[i];
    u16 h = f2bf(v);
    hi[i] = h;
    lo[i] = f2bf(v - bf2f(h));
  }
}

// ---------------------------------------------------------------------------
// X [b][CIN][14400] fp32 -> XT hi/lo [b][14400][CIN] bf16 (transpose + split)
// ---------------------------------------------------------------------------
template <int CIN>
__global__ __launch_bounds__(256) void convert_t(const float* __restrict__ X,
                                                 u16* __restrict__ xth,
                                                 u16* __restrict__ xtl) {
  __shared__ float ls[64][65];
  int b = blockIdx.z;
  int n0 = blockIdx.x * 64, k0 = blockIdx.y * 64;
  int t = threadIdx.x;
  int rt = t >> 4, c4 = (t & 15) * 4;
#pragma unroll
  for (int rr = 0; rr < 4; ++rr) {
    int kk = rr * 16 + rt;
    float4 v = *(const float4*)&X[((size_t)(b * CIN + k0 + kk)) * HW + n0 + c4];
    ls[kk][c4] = v.x; ls[kk][c4 + 1] = v.y; ls[kk][c4 + 2] = v.z; ls[kk][c4 + 3] = v.w;
  }
  __syncthreads();
#pragma unroll
  for (int rr = 0; rr < 4; ++rr) {
    int nn = rr * 16 + rt;
    float v0 = ls[c4 + 0][nn], v1 = ls[c4 + 1][nn], v2 = ls[c4 + 2][nn], v3 = ls[c4 + 3][nn];
    ushort4 oh, ol;
    oh.x = f2bf(v0); ol.x = f2bf(v0 - bf2f(oh.x));
    oh.y = f2bf(v1); ol.y = f2bf(v1 - bf2f(oh.y));
    oh.z = f2bf(v2); ol.z = f2bf(v2 - bf2f(oh.z));
    oh.w = f2bf(v3); ol.w = f2bf(v3 - bf2f(oh.w));
    size_t idx = ((size_t)(b * HW + n0 + nn)) * CIN + k0 + c4;
    *(ushort4*)&xth[idx] = oh;
    *(ushort4*)&xtl[idx] = ol;
  }
}

// ---------------------------------------------------------------------------
// Split-bf16 MFMA GEMM v5:  C[b][m][n] = epi( sum_k A[m][k]*B[b][n][k] )
//  Tile BM=128 x BN=192, BK=32, 8 waves (2m x 4n), acc[4][3] per wave
//  (identical wave/epilogue geometry to the harness-verified v4).
//  NEW: 3-slot LDS ring (3 x 40KB = 120KB, 1 block/CU), staged TWO k-steps
//  ahead via global_load_lds; per step:
//    s_waitcnt vmcnt(5)   <- leave stage(ks+1)'s 5 loads/wave in flight
//    s_barrier            <- all waves' stage(ks) landed
//    stage(ks+2)          <- slot (ks+2)%3; its last readers finished in
//                            step ks-1 (ds_reads lgkm-retired pre-barrier)
//    ds_read slot ks%3 ; setprio(1) ; 36 MFMA ; setprio(0)
//  Loads are never drained to 0 in the main loop (T3+T4); one barrier/step.
// ---------------------------------------------------------------------------
template <int K, int M_TOT, bool BNRELU>
__global__ __launch_bounds__(512, 2) void gemm_mfma(
    const u16* __restrict__ Ah, const u16* __restrict__ Al,
    const u16* __restrict__ Bh, const u16* __restrict__ Bl,
    float* __restrict__ C,
    const float* __restrict__ p0, const float* __restrict__ p1,
    const float* __restrict__ p2, const float* __restrict__ p3,
    const float* __restrict__ p4) {
  constexpr int NSTEP = K / 32;
  // frag-major ring: [slot][frag][lane*8].
  // sA frags: 0..7 = A hi (m-frags), 8..15 = A lo
  // sB frags: 0..11 = B hi (n-frags), 12..23 = B lo
  __shared__ alignas(16) u16 sA[3][16][512];
  __shared__ alignas(16) u16 sB[3][24][512];

  int t = threadIdx.x, w = t >> 6, l = t & 63;
  int wm = w >> 2, wn = w & 3;
  int b = blockIdx.z;
  int n0 = blockIdx.x * 192;
  int m0 = blockIdx.y * 128;

  int fr = l & 15, fkc = l >> 4;  // fragment row, k-chunk (of 8 u16)
  const size_t bOff = (size_t)b * HW;

  // stage one 32-k slice: 16 A frags + 24 B frags = 40 x 1KB; 5 per wave
  auto stage = [&](int ks, int slot) {
    int k0 = ks * 32;
#pragma unroll
    for (int c = 0; c < 5; ++c) {
      int i = w * 5 + c;
      const u16* g;
      u16* d;
      if (i < 8) {
        g = Ah + (size_t)(m0 + i * 16 + fr) * K + k0 + fkc * 8;
        d = &sA[slot][i][0];
      } else if (i < 16) {
        g = Al + (size_t)(m0 + (i - 8) * 16 + fr) * K + k0 + fkc * 8;
        d = &sA[slot][i][0];
      } else if (i < 28) {
        g = Bh + (bOff + n0 + (i - 16) * 16 + fr) * (size_t)K + k0 + fkc * 8;
        d = &sB[slot][i - 16][0];
      } else {
        g = Bl + (bOff + n0 + (i - 28) * 16 + fr) * (size_t)K + k0 + fkc * 8;
        d = &sB[slot][i - 16][0];  // i-16 in 12..23 -> lo frags
      }
      async16(d, g);
    }
  };

  f32x4 acc[4][3];
#pragma unroll
  for (int i = 0; i < 4; ++i)
#pragma unroll
    for (int j = 0; j < 3; ++j) acc[i][j] = (f32x4){0.f, 0.f, 0.f, 0.f};

  stage(0, 0);
  stage(1, 1);

  for (int ks = 0; ks < NSTEP; ++ks) {
    // wait own stage(ks) landed; keep stage(ks+1)'s 5 loads in flight
    if (ks + 1 < NSTEP)
      asm volatile("s_waitcnt vmcnt(5)" ::: "memory");
    else
      asm volatile("s_waitcnt vmcnt(0)" ::: "memory");
    __builtin_amdgcn_s_barrier();      // all waves' stage(ks) landed
    __builtin_amdgcn_sched_barrier(0); // pin: nothing moves above this point

    if (ks + 2 < NSTEP) stage(ks + 2, (ks + 2) % 3);

    int cur = ks % 3;
    bf16x8 bh[3], bl[3];
#pragma unroll
    for (int nt = 0; nt < 3; ++nt) {
      bh[nt] = *(const bf16x8*)&sB[cur][wn * 3 + nt][l * 8];
      bl[nt] = *(const bf16x8*)&sB[cur][12 + wn * 3 + nt][l * 8];
    }
    bf16x8 ah[4], al[4];
#pragma unroll
    for (int mt = 0; mt < 4; ++mt) {
      ah[mt] = *(const bf16x8*)&sA[cur][wm * 4 + mt][l * 8];
      al[mt] = *(const bf16x8*)&sA[cur][8 + wm * 4 + mt][l * 8];
    }
    __builtin_amdgcn_s_setprio(1);
#pragma unroll
    for (int mt = 0; mt < 4; ++mt)
#pragma unroll
      for (int nt = 0; nt < 3; ++nt) {
        acc[mt][nt] = __builtin_amdgcn_mfma_f32_16x16x32_bf16(ah[mt], bh[nt], acc[mt][nt], 0, 0, 0);
        acc[mt][nt] = __builtin_amdgcn_mfma_f32_16x16x32_bf16(ah[mt], bl[nt], acc[mt][nt], 0, 0, 0);
        acc[mt][nt] = __builtin_amdgcn_mfma_f32_16x16x32_bf16(al[mt], bh[nt], acc[mt][nt], 0, 0, 0);
      }
    __builtin_amdgcn_s_setprio(0);
  }

  // epilogue: params via broadcast float4 loads (same addr across fr lanes)
#pragma unroll
  for (int mt = 0; mt < 4; ++mt) {
    int mb = m0 + (wm * 4 + mt) * 16 + (l >> 4) * 4;  // 4 consecutive m rows
    float iv[4], ad[4];
    if (BNRELU) {
      float4 g0 = *(const float4*)&p0[mb];
      float4 g1 = *(const float4*)&p1[mb];
      float4 g2 = *(const float4*)&p2[mb];
      float4 g3 = *(const float4*)&p3[mb];
      float4 g4 = *(const float4*)&p4[mb];
      iv[0] = g1.x * rsqrtf(g4.x + 1e-5f);
      iv[1] = g1.y * rsqrtf(g4.y + 1e-5f);
      iv[2] = g1.z * rsqrtf(g4.z + 1e-5f);
      iv[3] = g1.w * rsqrtf(g4.w + 1e-5f);
      ad[0] = (g0.x - g3.x) * iv[0] + g2.x;
      ad[1] = (g0.y - g3.y) * iv[1] + g2.y;
      ad[2] = (g0.z - g3.z) * iv[2] + g2.z;
      ad[3] = (g0.w - g3.w) * iv[3] + g2.w;
    } else {
      float4 g0 = *(const float4*)&p0[mb];
      ad[0] = g0.x; ad[1] = g0.y; ad[2] = g0.z; ad[3] = g0.w;
    }
#pragma unroll
    for (int nt = 0; nt < 3; ++nt) {
      int n = n0 + (wn * 3 + nt) * 16 + fr;
#pragma unroll
      for (int r = 0; r < 4; ++r) {
        float v = acc[mt][nt][r];
        if (BNRELU)
          v = fmaxf(v * iv[r] + ad[r], 0.f);
        else
          v = v + ad[r];
        C[((size_t)(b * M_TOT) + mb + r) * HW + n] = v;
      }
    }
  }
}

// ---------------------------------------------------------------------------
// valueT[b][cv][128] hi/lo = Wv[cv,:] . xp[b,:,s] + bv[cv]  (s>=110 -> 0)
// ---------------------------------------------------------------------------
__global__ __launch_bounds__(256) void value_kernel(
    const float* __restrict__ Wv, const float* __restrict__ xp,
    const float* __restrict__ bv, u16* __restrict__ vth,
    u16* __restrict__ vtl) {
  int b = blockIdx.x >> 7, s = blockIdx.x & 127;
  int t = threadIdx.x;
  size_t o = ((size_t)(b * 256 + t)) * 128 + s;
  if (s >= S_TOT) { vth[o] = 0; vtl[o] = 0; return; }
  __shared__ float xs[512];
  for (int i = t; i < 512; i += 256) xs[i] = xp[((size_t)b * 512 + i) * S_TOT + s];
  __syncthreads();
  float accv = 0.f;
  const float* wv = Wv + (size_t)t * 512;
  for (int k = 0; k < 512; k += 4) {
    float4 w4 = *(const float4*)&wv[k];
    accv += w4.x * xs[k] + w4.y * xs[k + 1] + w4.z * xs[k + 2] + w4.w * xs[k + 3];
  }
  accv += bv[t];
  u16 h = f2bf(accv);
  vth[o] = h;
  vtl[o] = f2bf(accv - bf2f(h));
}

// ---------------------------------------------------------------------------
// keypT[b][128][256] hi/lo from keyp [b][256][110] fp32 (s>=110 -> 0)
// ---------------------------------------------------------------------------
__global__ __launch_bounds__(256) void convert_key(const float* __restrict__ keyp,
                                                   u16* __restrict__ kth,
                                                   u16* __restrict__ ktl) {
  int b = blockIdx.x;
  int t = threadIdx.x;
  for (int i = t; i < 128 * 256; i += 256) {
    int s = i >> 8, c = i & 255;
    float v = (s < S_TOT) ? keyp[((size_t)(b * 256 + c)) * S_TOT + s] : 0.f;
    u16 h = f2bf(v);
    size_t o = ((size_t)(b * 128 + s)) * 256 + c;
    kth[o] = h;
    ktl[o] = f2bf(v - bf2f(h));
  }
}

// ---------------------------------------------------------------------------
// MFMA attention v2. Per block: 64 pixels, 4 waves. (unchanged)
// ---------------------------------------------------------------------------
__global__ __launch_bounds__(256) void attn_mfma(
    const u16* __restrict__ qh, const u16* __restrict__ ql,
    const u16* __restrict__ kh, const u16* __restrict__ kl,
    const u16* __restrict__ vh, const u16* __restrict__ vl,
    u16* __restrict__ aggh, u16* __restrict__ aggl) {
  __shared__ alignas(16) u16 lds[17408];
  int b = blockIdx.y, pix0 = blockIdx.x * 64;
  int t = threadIdx.x, w = t >> 6, l = t & 63;
  int fr = l & 15, q = l >> 4;

  const u16* kbase_h = kh + (size_t)b * 128 * 256;
  const u16* kbase_l = kl + (size_t)b * 128 * 256;

  f32x4 acc[8];
#pragma unroll
  for (int st = 0; st < 8; ++st) acc[st] = (f32x4){0.f, 0.f, 0.f, 0.f};

  const u16* qbh = qh + ((size_t)(b * HW + pix0 + w * 16 + fr)) * 256 + q * 8;
  const u16* qbl = ql + ((size_t)(b * HW + pix0 + w * 16 + fr)) * 256 + q * 8;

  auto stageK = [&](int ks, int buf) {
    int c0 = ks * 32;
#pragma unroll
    for (int j = 0; j < 4; ++j) {
      int i = t + j * 256;
      int half = i >> 9;
      int idx = i & 511;
      int st = idx >> 6, ll = idx & 63;
      const u16* src = (half ? kbase_l : kbase_h) +
                       (st * 16 + (ll & 15)) * 256 + c0 + (ll >> 4) * 8;
      async16(&lds[buf * 8192 + half * 4096 + idx * 8], src);
    }
  };

  stageK(0, 0);
  for (int ks = 0; ks < 8; ++ks) {
    __syncthreads();
    if (ks < 7) stageK(ks + 1, (ks + 1) & 1);
    bf16x8 ah = *(const bf16x8*)(qbh + ks * 32);
    bf16x8 al = *(const bf16x8*)(qbl + ks * 32);
    const u16* kb = &lds[(ks & 1) * 8192 + l * 8];
#pragma unroll
    for (int st = 0; st < 8; ++st) {
      bf16x8 bh = *(const bf16x8*)(kb + st * 512);
      bf16x8 bl = *(const bf16x8*)(kb + 4096 + st * 512);
      acc[st] = __builtin_amdgcn_mfma_f32_16x16x32_bf16(ah, bh, acc[st], 0, 0, 0);
      acc[st] = __builtin_amdgcn_mfma_f32_16x16x32_bf16(ah, bl, acc[st], 0, 0, 0);
      acc[st] = __builtin_amdgcn_mfma_f32_16x16x32_bf16(al, bh, acc[st], 0, 0, 0);
    }
  }

#pragma unroll
  for (int st = 0; st < 8; ++st)
#pragma unroll
    for (int r = 0; r < 4; ++r) acc[st][r] *= 0.0625f;
  if (fr >= 14) {
#pragma unroll
    for (int r = 0; r < 4; ++r) acc[6][r] = -1e30f;
  }
#pragma unroll
  for (int r = 0; r < 4; ++r) acc[7][r] = -1e30f;

#pragma unroll
  for (int r = 0; r < 4; ++r) {
    float m = -1e30f;
#pragma unroll
    for (int st = 0; st < 8; ++st) m = fmaxf(m, acc[st][r]);
    m = fmaxf(m, __shfl_xor(m, 1));
    m = fmaxf(m, __shfl_xor(m, 2));
    m = fmaxf(m, __shfl_xor(m, 4));
    m = fmaxf(m, __shfl_xor(m, 8));
    float s = 0.f;
#pragma unroll
    for (int st = 0; st < 8; ++st) {
      float e = __expf(acc[st][r] - m);
      acc[st][r] = e;
      s += e;
    }
    s += __shfl_xor(s, 1);
    s += __shfl_xor(s, 2);
    s += __shfl_xor(s, 4);
    s += __shfl_xor(s, 8);
    float inv = 1.f / s;
#pragma unroll
    for (int st = 0; st < 8; ++st) acc[st][r] *= inv;
  }

  __syncthreads();

  int prow = w * 16 + q * 4;
#pragma unroll
  for (int st = 0; st < 8; ++st) {
    int s = st * 16 + fr;
#pragma unroll
    for (int r = 0; r < 4; ++r) {
      float v = acc[st][r];
      u16 h = f2bf(v);
      lds[(prow + r) * 136 + s] = h;
      lds[8704 + (prow + r) * 136 + s] = f2bf(v - bf2f(h));
    }
  }
  __syncthreads();

  f32x4 oacc[4][4];
#pragma unroll
  for (int nt = 0; nt < 4; ++nt)
#pragma unroll
    for (int pt = 0; pt < 4; ++pt) oacc[nt][pt] = (f32x4){0.f, 0.f, 0.f, 0.f};

  const u16* vbh = vh + ((size_t)(b * 256 + w * 64 + fr)) * 128 + q * 8;
  const u16* vbl = vl + ((size_t)(b * 256 + w * 64 + fr)) * 128 + q * 8;

#pragma unroll
  for (int kc = 0; kc < 4; ++kc) {
    bf16x8 ph[4], pl[4];
#pragma unroll
    for (int pt = 0; pt < 4; ++pt) {
      ph[pt] = *(const bf16x8*)&lds[(pt * 16 + fr) * 136 + kc * 32 + q * 8];
      pl[pt] = *(const bf16x8*)&lds[8704 + (pt * 16 + fr) * 136 + kc * 32 + q * 8];
    }
#pragma unroll
    for (int nt = 0; nt < 4; ++nt) {
      bf16x8 a_h = *(const bf16x8*)(vbh + (size_t)nt * 16 * 128 + kc * 32);
      bf16x8 a_l = *(const bf16x8*)(vbl + (size_t)nt * 16 * 128 + kc * 32);
#pragma unroll
      for (int pt = 0; pt < 4; ++pt) {
        oacc[nt][pt] = __builtin_amdgcn_mfma_f32_16x16x32_bf16(a_h, ph[pt], oacc[nt][pt], 0, 0, 0);
        oacc[nt][pt] = __builtin_amdgcn_mfma_f32_16x16x32_bf16(a_h, pl[pt], oacc[nt][pt], 0, 0, 0);
        oacc[nt][pt] = __builtin_amdgcn_mfma_f32_16x16x32_bf16(a_l, ph[pt], oacc[nt][pt], 0, 0, 0);
      }
    }
  }

#pragma unroll
  for (int nt = 0; nt < 4; ++nt) {
#pragma unroll
    for (int pt = 0; pt < 4; ++pt) {
      ushort4 oh, ol;
      float v0 = oacc[nt][pt][0], v1 = oacc[nt][pt][1];
      float v2 = oacc[nt][pt][2], v3 = oacc[nt][pt][3];
      oh.x = f2bf(v0); ol.x = f2bf(v0 - bf2f(oh.x));
      oh.y = f2bf(v1); ol.y = f2bf(v1 - bf2f(oh.y));
      oh.z = f2bf(v2); ol.z = f2bf(v2 - bf2f(oh.z));
      oh.w = f2bf(v3); ol.w = f2bf(v3 - bf2f(oh.w));
      size_t o = ((size_t)(b * HW + pix0 + pt * 16 + fr)) * 256 + (w * 4 + nt) * 16 + q * 4;
      *(ushort4*)&aggh[o] = oh;
      *(ushort4*)&aggl[o] = ol;
    }
  }
}

extern "C" void kernel_launch(void* const* d_in, const int* in_sizes, int n_in,
                              void* d_out, int out_size, void* d_ws, size_t ws_size,
                              hipStream_t stream) {
  (void)in_sizes; (void)n_in; (void)out_size; (void)ws_size;
  const float* x     = (const float*)d_in[0];
  const float* Wk    = (const float*)d_in[1];
  const float* bk    = (const float*)d_in[2];
  const float* gamma = (const float*)d_in[3];
  const float* beta  = (const float*)d_in[4];
  const float* mean  = (const float*)d_in[5];
  const float* var   = (const float*)d_in[6];
  const float* Wv    = (const float*)d_in[7];
  const float* bv    = (const float*)d_in[8];
  const float* Wo    = (const float*)d_in[9];
  const float* bo    = (const float*)d_in[10];
  float* out = (float*)d_out;

  char* p = (char*)d_ws;
  float* kq = (float*)p;      p += (size_t)14745600 * 4;   // 4*256*14400 fp32
  u16* xth = (u16*)p;         p += (size_t)29491200 * 2;   // 4*14400*512 bf16
  u16* xtl = (u16*)p;         p += (size_t)29491200 * 2;
  u16* wkh = (u16*)p;         p += 131072 * 2;
  u16* wkl = (u16*)p;         p += 131072 * 2;
  u16* woh = (u16*)p;         p += 131072 * 2;
  u16* wol = (u16*)p;         p += 131072 * 2;
  float* xp = (float*)p;      p += (size_t)4 * 512 * 110 * 4;
  float* keyp = (float*)p;    p += (size_t)4 * 256 * 110 * 4;
  u16* vth = (u16*)p;         p += (size_t)4 * 256 * 128 * 2;
  u16* vtl = (u16*)p;         p += (size_t)4 * 256 * 128 * 2;
  u16* kth = (u16*)p;         p += (size_t)4 * 128 * 256 * 2;
  u16* ktl = (u16*)p;         p += (size_t)4 * 128 * 256 * 2;
  // aliases: xth/xtl (59MB each) are dead after gemm_kq.
  // first half -> agg hi/lo, second half -> kqT hi/lo
  u16* aggh = xth;
  u16* kqth = xth + (size_t)14745600;
  u16* aggl = xtl;
  u16* kqtl = xtl + (size_t)14745600;

  // weight splits
  convert_w<<<512, 256, 0, stream>>>(Wk, wkh, wkl, 256 * 512);
  convert_w<<<512, 256, 0, stream>>>(Wo, woh, wol, 512 * 256);
  // X -> transposed bf16 hi/lo
  convert_t<512><<<dim3(225, 8, 4), 256, 0, stream>>>(x, xth, xtl);
  // pyramid-pool x (pooling commutes with 1x1 conv for value)
  pool_kernel<<<dim3(4 * 512), dim3(256), 0, stream>>>(x, xp);
  // valueT = split(conv_v(pooled x) + bv), s-padded
  value_kernel<<<dim3(4 * 128), dim3(256), 0, stream>>>(Wv, xp, bv, vth, vtl);
  // kq = relu(BN(conv_k(x)))  [split-bf16 MFMA, ring-pipelined]
  gemm_mfma<512, 256, true><<<dim3(75, 2, 4), 512, 0, stream>>>(
      wkh, wkl, xth, xtl, kq, bk, gamma, beta, mean, var);
  // kqT (query in A-fragment layout)
  convert_t<256><<<dim3(225, 4, 4), 256, 0, stream>>>(kq, kqth, kqtl);
  // key = ppm(kq) -> keypT split, s-padded
  pool_kernel<<<dim3(4 * 256), dim3(256), 0, stream>>>(kq, keyp);
  convert_key<<<dim3(4), dim3(256), 0, stream>>>(keyp, kth, ktl);
  // fused MFMA attention -> agg split bf16
  attn_mfma<<<dim3(225, 4), 256, 0, stream>>>(kqth, kqtl, kth, ktl, vth, vtl,
                                              aggh, aggl);
  // out = conv_out(agg) + bo  [split-bf16 MFMA, ring-pipelined]
  gemm_mfma<256, 512, false><<<dim3(75, 4, 4), 512, 0, stream>>>(
      woh, wol, aggh, aggl, out, bo, nullptr, nullptr, nullptr, nullptr);
}

// Round 6
// 557.254 us; speedup vs baseline: 1.0592x; 1.0049x over previous
//
#include <hip/hip_runtime.h>
#include <cstdint>
#include <cstddef>

#define HW 14400
#define WIDTH 120
#define S_TOT 110

typedef unsigned short u16;
typedef __attribute__((ext_vector_type(8))) short bf16x8;
typedef __attribute__((ext_vector_type(4))) float f32x4;

__device__ __forceinline__ u16 f2bf(float x) {
  unsigned u = __float_as_uint(x);
  unsigned r = (u + 0x7fffu + ((u >> 16) & 1u)) >> 16;
  return (u16)r;
}
__device__ __forceinline__ float bf2f(u16 h) {
  return __uint_as_float((unsigned)h << 16);
}

__device__ __forceinline__ void async16(void* lds, const void* g) {
  __builtin_amdgcn_global_load_lds(
      (const __attribute__((address_space(1))) void*)g,
      (__attribute__((address_space(3))) void*)lds, 16, 0, 0);
}

// ---------------------------------------------------------------------------
// Pyramid pooling v2: in [nplanes][14400] -> out [nplanes][110]
// Coalesced 2-phase reduction: (1) per-band column sums (lane-consecutive
// addresses), (2) 5-wide window sums from LDS (stride 5, gcd(5,32)=1 ->
// conflict-free), (3) hierarchical pyramid sums (unchanged).
// ---------------------------------------------------------------------------
__global__ __launch_bounds__(256) void pool_kernel(const float* __restrict__ in,
                                                   float* __restrict__ outp) {
  __shared__ float colsum[2880];  // [24 bands][120 cols]
  __shared__ float part[576];     // [24][24] 5x5 tile sums
  const float* plane = in + (size_t)blockIdx.x * HW;
  int t = threadIdx.x;
  for (int i = t; i < 2880; i += 256) {
    int by = i / 120, x = i - by * 120;
    const float* p0 = plane + (by * 5) * WIDTH + x;
    colsum[i] = p0[0] + p0[WIDTH] + p0[2 * WIDTH] + p0[3 * WIDTH] + p0[4 * WIDTH];
  }
  __syncthreads();
  for (int bb = t; bb < 576; bb += 256) {
    int by = bb / 24, bx = bb - by * 24;
    const float* c = &colsum[by * 120 + bx * 5];
    part[bb] = c[0] + c[1] + c[2] + c[3] + c[4];
  }
  __syncthreads();
  if (t < S_TOT) {
    float s = 0.f;
    if (t == 0) {
      for (int i = 0; i < 576; ++i) s += part[i];
      s *= (1.f / 14400.f);
    } else if (t < 10) {
      int idx = t - 1, i = idx / 3, j = idx % 3;
      for (int a = 0; a < 8; ++a)
        for (int c = 0; c < 8; ++c) s += part[(i * 8 + a) * 24 + (j * 8 + c)];
      s *= (1.f / 1600.f);
    } else if (t < 46) {
      int idx = t - 10, i = idx / 6, j = idx % 6;
      for (int a = 0; a < 4; ++a)
        for (int c = 0; c < 4; ++c) s += part[(i * 4 + a) * 24 + (j * 4 + c)];
      s *= (1.f / 400.f);
    } else {
      int idx = t - 46, i = idx / 8, j = idx % 8;
      for (int a = 0; a < 3; ++a)
        for (int c = 0; c < 3; ++c) s += part[(i * 3 + a) * 24 + (j * 3 + c)];
      s *= (1.f / 225.f);
    }
    outp[(size_t)blockIdx.x * S_TOT + t] = s;
  }
}

// ---------------------------------------------------------------------------
// Split fp32 weight -> bf16 hi/lo (elementwise)
// ---------------------------------------------------------------------------
__global__ __launch_bounds__(256) void convert_w(const float* __restrict__ in,
                                                 u16* __restrict__ hi,
                                                 u16* __restrict__ lo, int n) {
  int i = blockIdx.x * 256 + threadIdx.x;
  if (i < n) {
    float v = in[i];
    u16 h = f2bf(v);
    hi[i] = h;
    lo[i] = f2bf(v - bf2f(h));
  }
}

// ---------------------------------------------------------------------------
// X [b][CIN][14400] fp32 -> XT hi/lo [b][14400][CIN] bf16 (transpose + split)
// ---------------------------------------------------------------------------
template <int CIN>
__global__ __launch_bounds__(256) void convert_t(const float* __restrict__ X,
                                                 u16* __restrict__ xth,
                                                 u16* __restrict__ xtl) {
  __shared__ float ls[64][65];
  int b = blockIdx.z;
  int n0 = blockIdx.x * 64, k0 = blockIdx.y * 64;
  int t = threadIdx.x;
  int rt = t >> 4, c4 = (t & 15) * 4;
#pragma unroll
  for (int rr = 0; rr < 4; ++rr) {
    int kk = rr * 16 + rt;
    float4 v = *(const float4*)&X[((size_t)(b * CIN + k0 + kk)) * HW + n0 + c4];
    ls[kk][c4] = v.x; ls[kk][c4 + 1] = v.y; ls[kk][c4 + 2] = v.z; ls[kk][c4 + 3] = v.w;
  }
  __syncthreads();
#pragma unroll
  for (int rr = 0; rr < 4; ++rr) {
    int nn = rr * 16 + rt;
    float v0 = ls[c4 + 0][nn], v1 = ls[c4 + 1][nn], v2 = ls[c4 + 2][nn], v3 = ls[c4 + 3][nn];
    ushort4 oh, ol;
    oh.x = f2bf(v0); ol.x = f2bf(v0 - bf2f(oh.x));
    oh.y = f2bf(v1); ol.y = f2bf(v1 - bf2f(oh.y));
    oh.z = f2bf(v2); ol.z = f2bf(v2 - bf2f(oh.z));
    oh.w = f2bf(v3); ol.w = f2bf(v3 - bf2f(oh.w));
    size_t idx = ((size_t)(b * HW + n0 + nn)) * CIN + k0 + c4;
    *(ushort4*)&xth[idx] = oh;
    *(ushort4*)&xtl[idx] = ol;
  }
}

// ---------------------------------------------------------------------------
// Split-bf16 MFMA GEMM v6:  C[b][m][n] = epi( sum_k A[m][k]*B[b][n][k] )
//  Main loop identical to harness-verified v5 (3-slot ring, counted vmcnt,
//  setprio around MFMA cluster). Unified smem so the 120KB ring can be
//  reused by the NEW fused-kqT epilogue (BNRELU path, Th != null):
//  epilogue splits v into bf16 hi/lo, writes an LDS transpose buffer
//  [192 n][136 pitch] (<=2-way banks, 16B-aligned rows), then stores
//  coalesced 16B/lane rows to Th/Tl ([b][pix][M_TOT] layout == attn's Q
//  operand). Replaces the separate convert_t<256> dispatch; values are
//  bit-identical (same fp32 input to the same split).
// ---------------------------------------------------------------------------
template <int K, int M_TOT, bool BNRELU>
__global__ __launch_bounds__(512, 2) void gemm_mfma(
    const u16* __restrict__ Ah, const u16* __restrict__ Al,
    const u16* __restrict__ Bh, const u16* __restrict__ Bl,
    float* __restrict__ C,
    const float* __restrict__ p0, const float* __restrict__ p1,
    const float* __restrict__ p2, const float* __restrict__ p3,
    const float* __restrict__ p4,
    u16* __restrict__ Th, u16* __restrict__ Tl) {
  constexpr int NSTEP = K / 32;
  // unified: ring sA = smem[0..24576), ring sB = smem[24576..61440)
  // epilogue transpose: hi = smem[0..26112), lo = smem[26112..52224)
  __shared__ alignas(16) u16 smem[61440];

  int t = threadIdx.x, w = t >> 6, l = t & 63;
  int wm = w >> 2, wn = w & 3;
  int b = blockIdx.z;
  int n0 = blockIdx.x * 192;
  int m0 = blockIdx.y * 128;

  int fr = l & 15, fkc = l >> 4;  // fragment row, k-chunk (of 8 u16)
  const size_t bOff = (size_t)b * HW;

  // stage one 32-k slice: 16 A frags + 24 B frags = 40 x 1KB; 5 per wave
  auto stage = [&](int ks, int slot) {
    int k0 = ks * 32;
#pragma unroll
    for (int c = 0; c < 5; ++c) {
      int i = w * 5 + c;
      const u16* g;
      u16* d;
      if (i < 8) {
        g = Ah + (size_t)(m0 + i * 16 + fr) * K + k0 + fkc * 8;
        d = &smem[slot * 8192 + i * 512];
      } else if (i < 16) {
        g = Al + (size_t)(m0 + (i - 8) * 16 + fr) * K + k0 + fkc * 8;
        d = &smem[slot * 8192 + i * 512];
      } else if (i < 28) {
        g = Bh + (bOff + n0 + (i - 16) * 16 + fr) * (size_t)K + k0 + fkc * 8;
        d = &smem[24576 + slot * 12288 + (i - 16) * 512];
      } else {
        g = Bl + (bOff + n0 + (i - 28) * 16 + fr) * (size_t)K + k0 + fkc * 8;
        d = &smem[24576 + slot * 12288 + (i - 16) * 512];  // frags 12..23 = lo
      }
      async16(d, g);
    }
  };

  f32x4 acc[4][3];
#pragma unroll
  for (int i = 0; i < 4; ++i)
#pragma unroll
    for (int j = 0; j < 3; ++j) acc[i][j] = (f32x4){0.f, 0.f, 0.f, 0.f};

  stage(0, 0);
  stage(1, 1);

  for (int ks = 0; ks < NSTEP; ++ks) {
    // wait own stage(ks) landed; keep stage(ks+1)'s 5 loads in flight
    if (ks + 1 < NSTEP)
      asm volatile("s_waitcnt vmcnt(5)" ::: "memory");
    else
      asm volatile("s_waitcnt vmcnt(0)" ::: "memory");
    __builtin_amdgcn_s_barrier();      // all waves' stage(ks) landed
    __builtin_amdgcn_sched_barrier(0); // pin: nothing moves above this point

    if (ks + 2 < NSTEP) stage(ks + 2, (ks + 2) % 3);

    int cur = ks % 3;
    bf16x8 bh[3], bl[3];
#pragma unroll
    for (int nt = 0; nt < 3; ++nt) {
      bh[nt] = *(const bf16x8*)&smem[24576 + cur * 12288 + (wn * 3 + nt) * 512 + l * 8];
      bl[nt] = *(const bf16x8*)&smem[24576 + cur * 12288 + (12 + wn * 3 + nt) * 512 + l * 8];
    }
    bf16x8 ah[4], al[4];
#pragma unroll
    for (int mt = 0; mt < 4; ++mt) {
      ah[mt] = *(const bf16x8*)&smem[cur * 8192 + (wm * 4 + mt) * 512 + l * 8];
      al[mt] = *(const bf16x8*)&smem[cur * 8192 + (8 + wm * 4 + mt) * 512 + l * 8];
    }
    __builtin_amdgcn_s_setprio(1);
#pragma unroll
    for (int mt = 0; mt < 4; ++mt)
#pragma unroll
      for (int nt = 0; nt < 3; ++nt) {
        acc[mt][nt] = __builtin_amdgcn_mfma_f32_16x16x32_bf16(ah[mt], bh[nt], acc[mt][nt], 0, 0, 0);
        acc[mt][nt] = __builtin_amdgcn_mfma_f32_16x16x32_bf16(ah[mt], bl[nt], acc[mt][nt], 0, 0, 0);
        acc[mt][nt] = __builtin_amdgcn_mfma_f32_16x16x32_bf16(al[mt], bh[nt], acc[mt][nt], 0, 0, 0);
      }
    __builtin_amdgcn_s_setprio(0);
  }

  __syncthreads();  // all ring LDS reads done before epilogue reuses smem

  int q4 = (l >> 4) * 4;
  // epilogue: params via broadcast float4 loads (same addr across fr lanes)
#pragma unroll
  for (int mt = 0; mt < 4; ++mt) {
    int mb = m0 + (wm * 4 + mt) * 16 + q4;  // 4 consecutive m rows
    float iv[4], ad[4];
    if (BNRELU) {
      float4 g0 = *(const float4*)&p0[mb];
      float4 g1 = *(const float4*)&p1[mb];
      float4 g2 = *(const float4*)&p2[mb];
      float4 g3 = *(const float4*)&p3[mb];
      float4 g4 = *(const float4*)&p4[mb];
      iv[0] = g1.x * rsqrtf(g4.x + 1e-5f);
      iv[1] = g1.y * rsqrtf(g4.y + 1e-5f);
      iv[2] = g1.z * rsqrtf(g4.z + 1e-5f);
      iv[3] = g1.w * rsqrtf(g4.w + 1e-5f);
      ad[0] = (g0.x - g3.x) * iv[0] + g2.x;
      ad[1] = (g0.y - g3.y) * iv[1] + g2.y;
      ad[2] = (g0.z - g3.z) * iv[2] + g2.z;
      ad[3] = (g0.w - g3.w) * iv[3] + g2.w;
    } else {
      float4 g0 = *(const float4*)&p0[mb];
      ad[0] = g0.x; ad[1] = g0.y; ad[2] = g0.z; ad[3] = g0.w;
    }
#pragma unroll
    for (int nt = 0; nt < 3; ++nt) {
      int n = n0 + (wn * 3 + nt) * 16 + fr;
      float v[4];
#pragma unroll
      for (int r = 0; r < 4; ++r) {
        float x = acc[mt][nt][r];
        v[r] = BNRELU ? fmaxf(x * iv[r] + ad[r], 0.f) : x + ad[r];
        C[((size_t)(b * M_TOT) + mb + r) * HW + n] = v[r];
      }
      if (BNRELU && Th) {
        ushort4 hh, ll;
        hh.x = f2bf(v[0]); ll.x = f2bf(v[0] - bf2f(hh.x));
        hh.y = f2bf(v[1]); ll.y = f2bf(v[1] - bf2f(hh.y));
        hh.z = f2bf(v[2]); ll.z = f2bf(v[2] - bf2f(hh.z));
        hh.w = f2bf(v[3]); ll.w = f2bf(v[3] - bf2f(hh.w));
        int nl = (wn * 3 + nt) * 16 + fr;
        int ml = (wm * 4 + mt) * 16 + q4;
        *(ushort4*)&smem[nl * 136 + ml] = hh;
        *(ushort4*)&smem[26112 + nl * 136 + ml] = ll;
      }
    }
  }
  if (BNRELU && Th) {
    __syncthreads();
    // coalesced stores: row = pixel (n), 128 u16 of channels (m0..m0+128)
#pragma unroll
    for (int it = 0; it < 6; ++it) {
      int row = it * 32 + (t >> 4);
      int c8 = (t & 15) * 8;
      size_t go = (bOff + n0 + row) * (size_t)M_TOT + m0 + c8;
      *(bf16x8*)&Th[go] = *(const bf16x8*)&smem[row * 136 + c8];
      *(bf16x8*)&Tl[go] = *(const bf16x8*)&smem[26112 + row * 136 + c8];
    }
  }
}

// ---------------------------------------------------------------------------
// valueT[b][cv][128] hi/lo = Wv[cv,:] . xp[b,:,s] + bv[cv]  (s>=110 -> 0)
// ---------------------------------------------------------------------------
__global__ __launch_bounds__(256) void value_kernel(
    const float* __restrict__ Wv, const float* __restrict__ xp,
    const float* __restrict__ bv, u16* __restrict__ vth,
    u16* __restrict__ vtl) {
  int b = blockIdx.x >> 7, s = blockIdx.x & 127;
  int t = threadIdx.x;
  size_t o = ((size_t)(b * 256 + t)) * 128 + s;
  if (s >= S_TOT) { vth[o] = 0; vtl[o] = 0; return; }
  __shared__ float xs[512];
  for (int i = t; i < 512; i += 256) xs[i] = xp[((size_t)b * 512 + i) * S_TOT + s];
  __syncthreads();
  float accv = 0.f;
  const float* wv = Wv + (size_t)t * 512;
  for (int k = 0; k < 512; k += 4) {
    float4 w4 = *(const float4*)&wv[k];
    accv += w4.x * xs[k] + w4.y * xs[k + 1] + w4.z * xs[k + 2] + w4.w * xs[k + 3];
  }
  accv += bv[t];
  u16 h = f2bf(accv);
  vth[o] = h;
  vtl[o] = f2bf(accv - bf2f(h));
}

// ---------------------------------------------------------------------------
// keypT[b][128][256] hi/lo from keyp [b][256][110] fp32 (s>=110 -> 0)
// ---------------------------------------------------------------------------
__global__ __launch_bounds__(256) void convert_key(const float* __restrict__ keyp,
                                                   u16* __restrict__ kth,
                                                   u16* __restrict__ ktl) {
  int b = blockIdx.x;
  int t = threadIdx.x;
  for (int i = t; i < 128 * 256; i += 256) {
    int s = i >> 8, c = i & 255;
    float v = (s < S_TOT) ? keyp[((size_t)(b * 256 + c)) * S_TOT + s] : 0.f;
    u16 h = f2bf(v);
    size_t o = ((size_t)(b * 128 + s)) * 256 + c;
    kth[o] = h;
    ktl[o] = f2bf(v - bf2f(h));
  }
}

// ---------------------------------------------------------------------------
// MFMA attention v2. Per block: 64 pixels, 4 waves. (unchanged)
// ---------------------------------------------------------------------------
__global__ __launch_bounds__(256) void attn_mfma(
    const u16* __restrict__ qh, const u16* __restrict__ ql,
    const u16* __restrict__ kh, const u16* __restrict__ kl,
    const u16* __restrict__ vh, const u16* __restrict__ vl,
    u16* __restrict__ aggh, u16* __restrict__ aggl) {
  __shared__ alignas(16) u16 lds[17408];
  int b = blockIdx.y, pix0 = blockIdx.x * 64;
  int t = threadIdx.x, w = t >> 6, l = t & 63;
  int fr = l & 15, q = l >> 4;

  const u16* kbase_h = kh + (size_t)b * 128 * 256;
  const u16* kbase_l = kl + (size_t)b * 128 * 256;

  f32x4 acc[8];
#pragma unroll
  for (int st = 0; st < 8; ++st) acc[st] = (f32x4){0.f, 0.f, 0.f, 0.f};

  const u16* qbh = qh + ((size_t)(b * HW + pix0 + w * 16 + fr)) * 256 + q * 8;
  const u16* qbl = ql + ((size_t)(b * HW + pix0 + w * 16 + fr)) * 256 + q * 8;

  auto stageK = [&](int ks, int buf) {
    int c0 = ks * 32;
#pragma unroll
    for (int j = 0; j < 4; ++j) {
      int i = t + j * 256;
      int half = i >> 9;
      int idx = i & 511;
      int st = idx >> 6, ll = idx & 63;
      const u16* src = (half ? kbase_l : kbase_h) +
                       (st * 16 + (ll & 15)) * 256 + c0 + (ll >> 4) * 8;
      async16(&lds[buf * 8192 + half * 4096 + idx * 8], src);
    }
  };

  stageK(0, 0);
  for (int ks = 0; ks < 8; ++ks) {
    __syncthreads();
    if (ks < 7) stageK(ks + 1, (ks + 1) & 1);
    bf16x8 ah = *(const bf16x8*)(qbh + ks * 32);
    bf16x8 al = *(const bf16x8*)(qbl + ks * 32);
    const u16* kb = &lds[(ks & 1) * 8192 + l * 8];
#pragma unroll
    for (int st = 0; st < 8; ++st) {
      bf16x8 bh = *(const bf16x8*)(kb + st * 512);
      bf16x8 bl = *(const bf16x8*)(kb + 4096 + st * 512);
      acc[st] = __builtin_amdgcn_mfma_f32_16x16x32_bf16(ah, bh, acc[st], 0, 0, 0);
      acc[st] = __builtin_amdgcn_mfma_f32_16x16x32_bf16(ah, bl, acc[st], 0, 0, 0);
      acc[st] = __builtin_amdgcn_mfma_f32_16x16x32_bf16(al, bh, acc[st], 0, 0, 0);
    }
  }

#pragma unroll
  for (int st = 0; st < 8; ++st)
#pragma unroll
    for (int r = 0; r < 4; ++r) acc[st][r] *= 0.0625f;
  if (fr >= 14) {
#pragma unroll
    for (int r = 0; r < 4; ++r) acc[6][r] = -1e30f;
  }
#pragma unroll
  for (int r = 0; r < 4; ++r) acc[7][r] = -1e30f;

#pragma unroll
  for (int r = 0; r < 4; ++r) {
    float m = -1e30f;
#pragma unroll
    for (int st = 0; st < 8; ++st) m = fmaxf(m, acc[st][r]);
    m = fmaxf(m, __shfl_xor(m, 1));
    m = fmaxf(m, __shfl_xor(m, 2));
    m = fmaxf(m, __shfl_xor(m, 4));
    m = fmaxf(m, __shfl_xor(m, 8));
    float s = 0.f;
#pragma unroll
    for (int st = 0; st < 8; ++st) {
      float e = __expf(acc[st][r] - m);
      acc[st][r] = e;
      s += e;
    }
    s += __shfl_xor(s, 1);
    s += __shfl_xor(s, 2);
    s += __shfl_xor(s, 4);
    s += __shfl_xor(s, 8);
    float inv = 1.f / s;
#pragma unroll
    for (int st = 0; st < 8; ++st) acc[st][r] *= inv;
  }

  __syncthreads();

  int prow = w * 16 + q * 4;
#pragma unroll
  for (int st = 0; st < 8; ++st) {
    int s = st * 16 + fr;
#pragma unroll
    for (int r = 0; r < 4; ++r) {
      float v = acc[st][r];
      u16 h = f2bf(v);
      lds[(prow + r) * 136 + s] = h;
      lds[8704 + (prow + r) * 136 + s] = f2bf(v - bf2f(h));
    }
  }
  __syncthreads();

  f32x4 oacc[4][4];
#pragma unroll
  for (int nt = 0; nt < 4; ++nt)
#pragma unroll
    for (int pt = 0; pt < 4; ++pt) oacc[nt][pt] = (f32x4){0.f, 0.f, 0.f, 0.f};

  const u16* vbh = vh + ((size_t)(b * 256 + w * 64 + fr)) * 128 + q * 8;
  const u16* vbl = vl + ((size_t)(b * 256 + w * 64 + fr)) * 128 + q * 8;

#pragma unroll
  for (int kc = 0; kc < 4; ++kc) {
    bf16x8 ph[4], pl[4];
#pragma unroll
    for (int pt = 0; pt < 4; ++pt) {
      ph[pt] = *(const bf16x8*)&lds[(pt * 16 + fr) * 136 + kc * 32 + q * 8];
      pl[pt] = *(const bf16x8*)&lds[8704 + (pt * 16 + fr) * 136 + kc * 32 + q * 8];
    }
#pragma unroll
    for (int nt = 0; nt < 4; ++nt) {
      bf16x8 a_h = *(const bf16x8*)(vbh + (size_t)nt * 16 * 128 + kc * 32);
      bf16x8 a_l = *(const bf16x8*)(vbl + (size_t)nt * 16 * 128 + kc * 32);
#pragma unroll
      for (int pt = 0; pt < 4; ++pt) {
        oacc[nt][pt] = __builtin_amdgcn_mfma_f32_16x16x32_bf16(a_h, ph[pt], oacc[nt][pt], 0, 0, 0);
        oacc[nt][pt] = __builtin_amdgcn_mfma_f32_16x16x32_bf16(a_h, pl[pt], oacc[nt][pt], 0, 0, 0);
        oacc[nt][pt] = __builtin_amdgcn_mfma_f32_16x16x32_bf16(a_l, ph[pt], oacc[nt][pt], 0, 0, 0);
      }
    }
  }

#pragma unroll
  for (int nt = 0; nt < 4; ++nt) {
#pragma unroll
    for (int pt = 0; pt < 4; ++pt) {
      ushort4 oh, ol;
      float v0 = oacc[nt][pt][0], v1 = oacc[nt][pt][1];
      float v2 = oacc[nt][pt][2], v3 = oacc[nt][pt][3];
      oh.x = f2bf(v0); ol.x = f2bf(v0 - bf2f(oh.x));
      oh.y = f2bf(v1); ol.y = f2bf(v1 - bf2f(oh.y));
      oh.z = f2bf(v2); ol.z = f2bf(v2 - bf2f(oh.z));
      oh.w = f2bf(v3); ol.w = f2bf(v3 - bf2f(oh.w));
      size_t o = ((size_t)(b * HW + pix0 + pt * 16 + fr)) * 256 + (w * 4 + nt) * 16 + q * 4;
      *(ushort4*)&aggh[o] = oh;
      *(ushort4*)&aggl[o] = ol;
    }
  }
}

extern "C" void kernel_launch(void* const* d_in, const int* in_sizes, int n_in,
                              void* d_out, int out_size, void* d_ws, size_t ws_size,
                              hipStream_t stream) {
  (void)in_sizes; (void)n_in; (void)out_size;
  const float* x     = (const float*)d_in[0];
  const float* Wk    = (const float*)d_in[1];
  const float* bk    = (const float*)d_in[2];
  const float* gamma = (const float*)d_in[3];
  const float* beta  = (const float*)d_in[4];
  const float* mean  = (const float*)d_in[5];
  const float* var   = (const float*)d_in[6];
  const float* Wv    = (const float*)d_in[7];
  const float* bv    = (const float*)d_in[8];
  const float* Wo    = (const float*)d_in[9];
  const float* bo    = (const float*)d_in[10];
  float* out = (float*)d_out;

  char* p = (char*)d_ws;
  float* kq = (float*)p;      p += (size_t)14745600 * 4;   // 4*256*14400 fp32
  u16* xth = (u16*)p;         p += (size_t)29491200 * 2;   // 4*14400*512 bf16
  u16* xtl = (u16*)p;         p += (size_t)29491200 * 2;
  u16* wkh = (u16*)p;         p += 131072 * 2;
  u16* wkl = (u16*)p;         p += 131072 * 2;
  u16* woh = (u16*)p;         p += 131072 * 2;
  u16* wol = (u16*)p;         p += 131072 * 2;
  float* xp = (float*)p;      p += (size_t)4 * 512 * 110 * 4;
  float* keyp = (float*)p;    p += (size_t)4 * 256 * 110 * 4;
  u16* vth = (u16*)p;         p += (size_t)4 * 256 * 128 * 2;
  u16* vtl = (u16*)p;         p += (size_t)4 * 256 * 128 * 2;
  u16* kth = (u16*)p;         p += (size_t)4 * 128 * 256 * 2;
  u16* ktl = (u16*)p;         p += (size_t)4 * 128 * 256 * 2;
  // fused kqT needs dedicated buffers (cannot alias xth/xtl: gemm_kq reads
  // those as B while writing kqT). Fallback to convert_t<256> if ws short.
  u16* kqth_f = (u16*)p;      p += (size_t)14745600 * 2;   // 4*14400*256 bf16
  u16* kqtl_f = (u16*)p;      p += (size_t)14745600 * 2;
  bool fused = ((size_t)(p - (char*)d_ws) <= ws_size);

  // aliases: xth/xtl (59MB each) are dead after gemm_kq.
  // first half -> agg hi/lo; second half -> kqT hi/lo (fallback only)
  u16* aggh = xth;
  u16* aggl = xtl;
  u16* kqth = fused ? kqth_f : xth + (size_t)14745600;
  u16* kqtl = fused ? kqtl_f : xtl + (size_t)14745600;

  // weight splits
  convert_w<<<512, 256, 0, stream>>>(Wk, wkh, wkl, 256 * 512);
  convert_w<<<512, 256, 0, stream>>>(Wo, woh, wol, 512 * 256);
  // X -> transposed bf16 hi/lo
  convert_t<512><<<dim3(225, 8, 4), 256, 0, stream>>>(x, xth, xtl);
  // pyramid-pool x (pooling commutes with 1x1 conv for value)
  pool_kernel<<<dim3(4 * 512), dim3(256), 0, stream>>>(x, xp);
  // valueT = split(conv_v(pooled x) + bv), s-padded
  value_kernel<<<dim3(4 * 128), dim3(256), 0, stream>>>(Wv, xp, bv, vth, vtl);
  // kq = relu(BN(conv_k(x)))  [ring-pipelined; fused coalesced kqT store]
  gemm_mfma<512, 256, true><<<dim3(75, 2, 4), 512, 0, stream>>>(
      wkh, wkl, xth, xtl, kq, bk, gamma, beta, mean, var,
      fused ? kqth : (u16*)nullptr, fused ? kqtl : (u16*)nullptr);
  // kqT (query in A-fragment layout) -- only if not fused
  if (!fused)
    convert_t<256><<<dim3(225, 4, 4), 256, 0, stream>>>(kq, kqth, kqtl);
  // key = ppm(kq) -> keypT split, s-padded
  pool_kernel<<<dim3(4 * 256), dim3(256), 0, stream>>>(kq, keyp);
  convert_key<<<dim3(4), dim3(256), 0, stream>>>(keyp, kth, ktl);
  // fused MFMA attention -> agg split bf16
  attn_mfma<<<dim3(225, 4), 256, 0, stream>>>(kqth, kqtl, kth, ktl, vth, vtl,
                                              aggh, aggl);
  // out = conv_out(agg) + bo  [ring-pipelined]
  gemm_mfma<256, 512, false><<<dim3(75, 4, 4), 512, 0, stream>>>(
      woh, wol, aggh, aggl, out, bo, nullptr, nullptr, nullptr, nullptr,
      nullptr, nullptr);
}